// Round 6
// baseline (337.693 us; speedup 1.0000x reference)
//
#include <hip/hip_runtime.h>

typedef unsigned short u16;
typedef unsigned int u32;

static __device__ __forceinline__ float lrelu(float x) { return x >= 0.f ? x : 0.2f * x; }

// f32 -> bf16 round-to-nearest-even (bit trick; no NaN in this workload)
static __device__ __forceinline__ u16 f2bf(float f) {
    u32 u = __float_as_uint(f);
    u += 0x7FFF + ((u >> 16) & 1);
    return (u16)(u >> 16);
}
static __device__ __forceinline__ float bf2f(u16 h) {
    return __uint_as_float((u32)h << 16);
}

// ---- GEMM: Hb = X @ W (bf16 out) + fused a_s/a_d; handles full graph then group graph ----
__global__ __launch_bounds__(256) void gemm_both_kernel(
        const float* __restrict__ Xf, const float* __restrict__ Wf,
        const float* __restrict__ asf, const float* __restrict__ adf,
        u16* __restrict__ Hbf, float* __restrict__ as_f, float* __restrict__ ad_f, int N,
        const float* __restrict__ Xg, const float* __restrict__ Wg,
        const float* __restrict__ asg, const float* __restrict__ adg,
        u16* __restrict__ Hbg, float* __restrict__ as_g, float* __restrict__ ad_g, int G,
        int nbFull) {
    const float* X; const float* W; const float* av; const float* dv;
    u16* Hb; float* as_out; float* ad_out; int n_lim; long base;
    if (blockIdx.x < nbFull) {
        X = Xf; W = Wf; av = asf; dv = adf; Hb = Hbf; as_out = as_f; ad_out = ad_f;
        n_lim = N; base = (long)blockIdx.x * 32;
    } else {
        X = Xg; W = Wg; av = asg; dv = adg; Hb = Hbg; as_out = as_g; ad_out = ad_g;
        n_lim = G; base = (long)(blockIdx.x - nbFull) * 32;
    }
    __shared__ float Ws[64 * 128];   // 32 KB (half of W)
    __shared__ float Xs[32 * 128];   // 16 KB (32 node rows)
    int tid = threadIdx.x;
    float4* Ws4 = (float4*)Ws;
    float4* Xs4 = (float4*)Xs;
    const float4* X4 = (const float4*)(X + base * 128);
    for (int i = tid; i < 1024; i += 256) {
        int r = i >> 5;
        Xs4[i] = (base + r < n_lim) ? X4[i] : make_float4(0.f, 0.f, 0.f, 0.f);
    }
    int fgrp = tid & 31;        // feature float4 index (0..31)
    int n0 = (tid >> 5) * 4;    // local node quad (0..28)
    float4 acc[4] = {};
    for (int half = 0; half < 2; ++half) {
        __syncthreads();
        const float4* W4 = (const float4*)(W + half * 64 * 128);
        for (int i = tid; i < 2048; i += 256) Ws4[i] = W4[i];
        __syncthreads();
        #pragma unroll 4
        for (int kk = 0; kk < 64; ++kk) {
            float4 w = Ws4[kk * 32 + fgrp];
            #pragma unroll
            for (int j = 0; j < 4; ++j) {
                float x = Xs[(n0 + j) * 128 + half * 64 + kk];
                acc[j].x += x * w.x; acc[j].y += x * w.y;
                acc[j].z += x * w.z; acc[j].w += x * w.w;
            }
        }
    }
    float4 as4 = ((const float4*)av)[fgrp];
    float4 ad4 = ((const float4*)dv)[fgrp];
    float ps[4], pd[4];
    #pragma unroll
    for (int j = 0; j < 4; ++j) {
        ps[j] = acc[j].x * as4.x + acc[j].y * as4.y + acc[j].z * as4.z + acc[j].w * as4.w;
        pd[j] = acc[j].x * ad4.x + acc[j].y * ad4.y + acc[j].z * ad4.z + acc[j].w * ad4.w;
    }
    #pragma unroll
    for (int off = 16; off; off >>= 1) {
        #pragma unroll
        for (int j = 0; j < 4; ++j) {
            ps[j] += __shfl_xor(ps[j], off);
            pd[j] += __shfl_xor(pd[j], off);
        }
    }
    if ((tid & 31) == 0) {
        #pragma unroll
        for (int j = 0; j < 4; ++j) {
            long n = base + n0 + j;
            if (n < n_lim) { as_out[n] = ps[j]; ad_out[n] = pd[j]; }
        }
    }
    #pragma unroll
    for (int j = 0; j < 4; ++j) {
        long n = base + n0 + j;
        if (n < n_lim) {
            ushort4 hv;
            hv.x = f2bf(acc[j].x); hv.y = f2bf(acc[j].y);
            hv.z = f2bf(acc[j].z); hv.w = f2bf(acc[j].w);
            ((ushort4*)(Hb + n * 128))[fgrp] = hv;
        }
    }
}

// ---------------- merged CSR build over both graphs ----------------
// deg/offs layout: [0,N) full nodes, [N,Npad) zero pad, [Npad,Npad+G) group nodes
__global__ __launch_bounds__(256) void hist2_kernel(const int* __restrict__ efd, int E, int N,
                                                    const int* __restrict__ egd, int Eg, int G,
                                                    int Npad, int* __restrict__ deg) {
    int i = blockIdx.x * 256 + threadIdx.x;
    int totF = E + N;
    int tot = totF + Eg + G;
    if (i >= tot) return;
    int d;
    if (i < E) d = efd[i];
    else if (i < totF) d = i - E;
    else {
        int j = i - totF;
        d = Npad + ((j < Eg) ? egd[j] : (j - Eg));
    }
    atomicAdd(&deg[d], 1);
}

__global__ __launch_bounds__(256) void scan1_kernel(const int* __restrict__ deg, int n,
                                                    int* __restrict__ bsum) {
    __shared__ int s[256];
    int i = blockIdx.x * 256 + threadIdx.x;
    s[threadIdx.x] = (i < n) ? deg[i] : 0;
    __syncthreads();
    for (int off = 128; off; off >>= 1) {
        if (threadIdx.x < off) s[threadIdx.x] += s[threadIdx.x + off];
        __syncthreads();
    }
    if (threadIdx.x == 0) bsum[blockIdx.x] = s[0];
}

// per-element exclusive scan; each block redundantly scans the (raw) bsum array in LDS
// to derive its own block offset -> no separate scan2 kernel. nb <= 256 required.
__global__ __launch_bounds__(256) void scan3_kernel(int* __restrict__ deg, int n, int nb,
                                                    const int* __restrict__ bsum,
                                                    int* __restrict__ offs, int Ltot) {
    __shared__ int sb[256];
    __shared__ int s[256];
    int t = threadIdx.x;
    sb[t] = (t < nb) ? bsum[t] : 0;
    __syncthreads();
    for (int off = 1; off < 256; off <<= 1) {
        int u = (t >= off) ? sb[t - off] : 0;
        __syncthreads();
        sb[t] += u;
        __syncthreads();
    }
    int blockOff = (blockIdx.x == 0) ? 0 : sb[blockIdx.x - 1];
    if (blockIdx.x == 0 && t == 0) offs[Ltot] = sb[nb - 1];  // grand total

    int i = blockIdx.x * 256 + t;
    int v = (i < n) ? deg[i] : 0;
    s[t] = v;
    __syncthreads();
    for (int off = 1; off < 256; off <<= 1) {
        int u = (t >= off) ? s[t - off] : 0;
        __syncthreads();
        s[t] += u;
        __syncthreads();
    }
    if (i < n) {
        int excl = s[t] - v + blockOff;
        offs[i] = excl;
        deg[i] = excl;  // cursor for placement
    }
}

// placement + per-edge attention weight e = exp(lrelu(a_s[src]+a_d[dst])) computed ONCE
__global__ __launch_bounds__(256) void place2_kernel(const int* __restrict__ efs,
                                                     const int* __restrict__ efd, int E, int N,
                                                     const int* __restrict__ egs,
                                                     const int* __restrict__ egd, int Eg, int G,
                                                     int Npad,
                                                     const float* __restrict__ a_s,
                                                     const float* __restrict__ a_d,
                                                     const float* __restrict__ a_sg,
                                                     const float* __restrict__ a_dg,
                                                     int* __restrict__ cursor,
                                                     int* __restrict__ slot,
                                                     float* __restrict__ eslot) {
    int i = blockIdx.x * 256 + threadIdx.x;
    int totF = E + N;
    int tot = totF + Eg + G;
    if (i >= tot) return;
    int s, d, dcur;
    float av;
    if (i < totF) {
        if (i < E) { s = efs[i]; d = efd[i]; } else { s = d = i - E; }
        av = a_s[s] + a_d[d];
        dcur = d;
    } else {
        int j = i - totF;
        if (j < Eg) { s = egs[j]; d = egd[j]; } else { s = d = j - Eg; }
        av = a_sg[s] + a_dg[d];
        dcur = Npad + d;
    }
    float e = expf(lrelu(av));  // max-subtract skipped: alpha unchanged, no overflow (|av|<~10)
    int pos = atomicAdd(&cursor[dcur], 1);
    slot[pos] = s;
    eslot[pos] = e;
}

// ---------------- pull aggregation (both graphs): out = elu(sum(e*h)/sum(e) + bias) --------
__global__ __launch_bounds__(256) void pull2_kernel(const u16* __restrict__ Hf,
                                                    const u16* __restrict__ Hg,
                                                    const int* __restrict__ offs,
                                                    const int* __restrict__ slot,
                                                    const float* __restrict__ eslot,
                                                    const float* __restrict__ bias_f,
                                                    const float* __restrict__ bias_g,
                                                    float* __restrict__ fx,
                                                    float* __restrict__ gx,
                                                    int N, int G, int Npad) {
    int gid = blockIdx.x * 256 + threadIdx.x;
    int w = gid >> 6, lane = gid & 63;
    const u16* H;
    const float* bias;
    float* out;
    int idx;
    if (w < N) {
        H = Hf; bias = bias_f; out = fx + (long)w * 128; idx = w;
    } else if (w < N + G) {
        int g = w - N;
        H = Hg; bias = bias_g; out = gx + (long)g * 128; idx = Npad + g;
    } else return;
    int beg = offs[idx], end = offs[idx + 1];
    float accx = 0.f, accy = 0.f, ssum = 0.f;
    int k = beg;
    for (; k + 2 <= end; k += 2) {  // 2-way unroll: two gathers in flight
        int s0 = slot[k], s1 = slot[k + 1];
        float e0 = eslot[k], e1 = eslot[k + 1];
        ushort2 h0 = ((const ushort2*)H)[(long)s0 * 64 + lane];
        ushort2 h1 = ((const ushort2*)H)[(long)s1 * 64 + lane];
        accx += e0 * bf2f(h0.x) + e1 * bf2f(h1.x);
        accy += e0 * bf2f(h0.y) + e1 * bf2f(h1.y);
        ssum += e0 + e1;
    }
    if (k < end) {
        int s0 = slot[k];
        float e0 = eslot[k];
        ushort2 h0 = ((const ushort2*)H)[(long)s0 * 64 + lane];
        accx += e0 * bf2f(h0.x);
        accy += e0 * bf2f(h0.y);
        ssum += e0;
    }
    float inv = 1.f / ssum;  // >= 1 self-loop always present
    float2 b = ((const float2*)bias)[lane];
    float ox = accx * inv + b.x;
    float oy = accy * inv + b.y;
    ox = ox > 0.f ? ox : expm1f(ox);
    oy = oy > 0.f ? oy : expm1f(oy);
    ((float2*)out)[lane] = make_float2(ox, oy);
}

// ---------------- adjacent-group sum (atomics; tiny graph) ----------------
__global__ __launch_bounds__(256) void adj_kernel(const int* __restrict__ gsrc,
                                                  const int* __restrict__ gdst, int Eg,
                                                  const float* __restrict__ gx,
                                                  float* __restrict__ adj_sum,
                                                  float* __restrict__ cnt) {
    int gid = blockIdx.x * 256 + threadIdx.x;
    int i = gid >> 6, lane = gid & 63;
    if (i >= Eg) return;
    int s = gsrc[i], d = gdst[i];
    float2 gv = ((const float2*)gx)[(long)d * 64 + lane];
    atomicAdd(&adj_sum[(long)s * 128 + 2 * lane], gv.x);
    atomicAdd(&adj_sum[(long)s * 128 + 2 * lane + 1], gv.y);
    if (lane == 0) atomicAdd(&cnt[s], 1.f);
}

// ---------------- final: interaction + in-place updated + FC 128->16 ----------------
// FC reduce uses exchange-halves: 17 shfl total (vs 96 butterfly), result lands
// one class per 4-lane group: class c = (lane>>2)&15, coalesced 64B store.
__global__ __launch_bounds__(256) void final_kernel(const int* __restrict__ node_group,
                                                    const float* __restrict__ gx,
                                                    const float* __restrict__ adj_sum,
                                                    const float* __restrict__ cnt,
                                                    const float* __restrict__ fcW,
                                                    const float* __restrict__ fcb,
                                                    float* __restrict__ upd,  // in: fullx_elu
                                                    float* __restrict__ out, int N) {
    int gid = blockIdx.x * 256 + threadIdx.x;
    int n = gid >> 6, lane = gid & 63;
    if (n >= N) return;
    int g = node_group[n];
    float2 row = ((const float2*)upd)[(long)n * 64 + lane];
    float2 gf = ((const float2*)gx)[(long)g * 64 + lane];
    float inv_cnt = 1.f / fmaxf(cnt[g], 1.f);
    float2 amv = ((const float2*)adj_sum)[(long)g * 64 + lane];
    float amx = amv.x * inv_cnt, amy = amv.y * inv_cnt;
    float pg = row.x * gf.x + row.y * gf.y;
    float pa = row.x * amx + row.y * amy;
    #pragma unroll
    for (int off = 32; off; off >>= 1) {
        pg += __shfl_xor(pg, off);
        pa += __shfl_xor(pa, off);
    }
    float ux = row.x + pg * gf.x + pa * amx;
    float uy = row.y + pg * gf.y + pa * amy;
    ((float2*)upd)[(long)n * 64 + lane] = make_float2(ux, uy);

    // FC partials: this lane covers features j = 2*lane, 2*lane+1
    float v[16];
    const float4* fW4 = (const float4*)fcW;
    #pragma unroll
    for (int q = 0; q < 4; ++q) {
        float4 w0 = fW4[(2 * lane) * 4 + q];
        float4 w1 = fW4[(2 * lane + 1) * 4 + q];
        v[4 * q + 0] = ux * w0.x + uy * w1.x;
        v[4 * q + 1] = ux * w0.y + uy * w1.y;
        v[4 * q + 2] = ux * w0.z + uy * w1.z;
        v[4 * q + 3] = ux * w0.w + uy * w1.w;
    }
    // exchange-halves deinterleave across lane bits 5..2 (8+4+2+1 = 15 shfl)
    #pragma unroll
    for (int stage = 0; stage < 4; ++stage) {
        int width = 32 >> stage;   // xor distance
        int half = 8 >> stage;     // values exchanged per lane
        bool hi = (lane & width) != 0;
        #pragma unroll
        for (int c = 0; c < half; ++c) {
            float send = hi ? v[c] : v[c + half];
            float recv = __shfl_xor(send, width);
            float keep = hi ? v[c + half] : v[c];
            v[c] = keep + recv;
        }
    }
    // finish sum across lane bits 0..1 (2 shfl)
    v[0] += __shfl_xor(v[0], 1);
    v[0] += __shfl_xor(v[0], 2);
    int cls = (lane >> 2) & 15;  // bit3=lane5, bit2=lane4, bit1=lane3, bit0=lane2
    if ((lane & 3) == 0) out[(long)n * 16 + cls] = v[0] + fcb[cls];
}

extern "C" void kernel_launch(void* const* d_in, const int* in_sizes, int n_in,
                              void* d_out, int out_size, void* d_ws, size_t ws_size,
                              hipStream_t stream) {
    const float* x_full = (const float*)d_in[0];
    const float* x_group = (const float*)d_in[1];
    const float* W_full = (const float*)d_in[2];
    const float* a_src_full = (const float*)d_in[3];
    const float* a_dst_full = (const float*)d_in[4];
    const float* bias_full = (const float*)d_in[5];
    const float* W_group = (const float*)d_in[6];
    const float* a_src_g = (const float*)d_in[7];
    const float* a_dst_g = (const float*)d_in[8];
    const float* bias_g = (const float*)d_in[9];
    const float* fc_W = (const float*)d_in[10];
    const float* fc_b = (const float*)d_in[11];
    const int* ef = (const int*)d_in[12];
    const int* eg = (const int*)d_in[13];
    const int* node_group = (const int*)d_in[14];

    int N = in_sizes[0] / 128;
    int G = in_sizes[1] / 128;
    int E = in_sizes[12] / 2;
    int Eg = in_sizes[13] / 2;
    const int* ef_src = ef;
    const int* ef_dst = ef + E;
    const int* eg_src = eg;
    const int* eg_dst = eg + Eg;

    int Npad = (N + 255) & ~255;
    int Ltot = Npad + G;       // deg/offs logical length
    int LtotPad = (Ltot + 255) & ~255;
    int totF = E + N;
    int tot = totF + Eg + G;

    float* out_cls = (float*)d_out;
    float* fx = out_cls + (long)N * 16;  // fullx_elu scratch, becomes `updated`

    char* w = (char*)d_ws;
    auto alloc = [&](size_t bytes) {
        char* p = w;
        w += (bytes + 255) & ~(size_t)255;
        return p;
    };
    u16* h_full = (u16*)alloc((size_t)N * 128 * 2);
    u16* h_g = (u16*)alloc((size_t)G * 128 * 2);
    float* a_s = (float*)alloc((size_t)N * 4);
    float* a_d = (float*)alloc((size_t)N * 4);
    float* a_sg = (float*)alloc((size_t)G * 4);
    float* a_dg = (float*)alloc((size_t)G * 4);
    float* gx = (float*)alloc((size_t)G * 128 * 4);
    // zero-init span: adj_sum, cnt, deg (contiguous, one memset)
    float* adj_sum = (float*)alloc((size_t)G * 128 * 4);
    float* cnt = (float*)alloc((size_t)G * 4);
    int* deg = (int*)alloc((size_t)LtotPad * 4);
    int* offs = (int*)alloc((size_t)(LtotPad + 1) * 4);
    int* slot = (int*)alloc((size_t)tot * 4);
    float* eslot = (float*)alloc((size_t)tot * 4);
    int* bsum = (int*)alloc(256 * 4);

    size_t zero_span = (char*)(deg + LtotPad) - (char*)adj_sum;
    (void)hipMemsetAsync(adj_sum, 0, zero_span, stream);

    auto cdiv = [](int a, int b) { return (a + b - 1) / b; };

    // feature transforms + fused attention scalars (both graphs, one launch)
    int nbFull = cdiv(N, 32);
    gemm_both_kernel<<<nbFull + cdiv(G, 32), 256, 0, stream>>>(
        x_full, W_full, a_src_full, a_dst_full, h_full, a_s, a_d, N,
        x_group, W_group, a_src_g, a_dst_g, h_g, a_sg, a_dg, G, nbFull);

    // merged CSR build (hist -> scan1 -> scan3(with self bsum-scan) -> place)
    int nb = cdiv(Ltot, 256);
    hist2_kernel<<<cdiv(tot, 256), 256, 0, stream>>>(ef_dst, E, N, eg_dst, Eg, G, Npad, deg);
    scan1_kernel<<<nb, 256, 0, stream>>>(deg, Ltot, bsum);
    scan3_kernel<<<nb, 256, 0, stream>>>(deg, Ltot, nb, bsum, offs, Ltot);
    place2_kernel<<<cdiv(tot, 256), 256, 0, stream>>>(ef_src, ef_dst, E, N, eg_src, eg_dst,
                                                      Eg, G, Npad, a_s, a_d, a_sg, a_dg,
                                                      deg, slot, eslot);

    // pull aggregation for both graphs
    pull2_kernel<<<cdiv((N + G) * 64, 256), 256, 0, stream>>>(h_full, h_g, offs, slot, eslot,
                                                              bias_full, bias_g, fx, gx,
                                                              N, G, Npad);

    // adjacent-group sum + final fused interaction/FC
    adj_kernel<<<cdiv(Eg * 64, 256), 256, 0, stream>>>(eg_src, eg_dst, Eg, gx, adj_sum, cnt);
    final_kernel<<<cdiv(N * 64, 256), 256, 0, stream>>>(node_group, gx, adj_sum, cnt, fc_W,
                                                        fc_b, fx, out_cls, N);
}

// Round 7
// 315.437 us; speedup vs baseline: 1.0706x; 1.0706x over previous
//
#include <hip/hip_runtime.h>

typedef unsigned short u16;
typedef unsigned int u32;

static __device__ __forceinline__ float lrelu(float x) { return x >= 0.f ? x : 0.2f * x; }

static __device__ __forceinline__ u16 f2bf(float f) {
    u32 u = __float_as_uint(f);
    u += 0x7FFF + ((u >> 16) & 1);
    return (u16)(u >> 16);
}
static __device__ __forceinline__ float bf2f(u16 h) {
    return __uint_as_float((u32)h << 16);
}

// 128->16 matvec across one wave: lane holds features (2*lane, 2*lane+1) = (f0,f1).
// Returns class ((lane>>2)&15)'s sum in every lane (valid for (lane&3)==0 stores).
// Exchange-halves reduction, 17 shfl, ALL NAMED REGISTERS (no arrays -> no scratch).
static __device__ __forceinline__ float fc_reduce16(float f0, float f1, int lane,
                                                    const float4* __restrict__ fW4) {
    float4 w00 = fW4[(2 * lane) * 4 + 0], w01 = fW4[(2 * lane) * 4 + 1];
    float4 w02 = fW4[(2 * lane) * 4 + 2], w03 = fW4[(2 * lane) * 4 + 3];
    float4 w10 = fW4[(2 * lane + 1) * 4 + 0], w11 = fW4[(2 * lane + 1) * 4 + 1];
    float4 w12 = fW4[(2 * lane + 1) * 4 + 2], w13 = fW4[(2 * lane + 1) * 4 + 3];
    float4 q0, q1, q2, q3;
    q0.x = f0 * w00.x + f1 * w10.x; q0.y = f0 * w00.y + f1 * w10.y;
    q0.z = f0 * w00.z + f1 * w10.z; q0.w = f0 * w00.w + f1 * w10.w;
    q1.x = f0 * w01.x + f1 * w11.x; q1.y = f0 * w01.y + f1 * w11.y;
    q1.z = f0 * w01.z + f1 * w11.z; q1.w = f0 * w01.w + f1 * w11.w;
    q2.x = f0 * w02.x + f1 * w12.x; q2.y = f0 * w02.y + f1 * w12.y;
    q2.z = f0 * w02.z + f1 * w12.z; q2.w = f0 * w02.w + f1 * w12.w;
    q3.x = f0 * w03.x + f1 * w13.x; q3.y = f0 * w03.y + f1 * w13.y;
    q3.z = f0 * w03.z + f1 * w13.z; q3.w = f0 * w03.w + f1 * w13.w;
    bool h5 = (lane & 32) != 0, h4 = (lane & 16) != 0;
    bool h3 = (lane & 8) != 0, h2 = (lane & 4) != 0;
    // stage A: xor 32, exchange 8 values; class bit3 <- lane bit5
    float4 s0, s1, k0, k1;
    s0.x = h5 ? q0.x : q2.x; s0.y = h5 ? q0.y : q2.y;
    s0.z = h5 ? q0.z : q2.z; s0.w = h5 ? q0.w : q2.w;
    s1.x = h5 ? q1.x : q3.x; s1.y = h5 ? q1.y : q3.y;
    s1.z = h5 ? q1.z : q3.z; s1.w = h5 ? q1.w : q3.w;
    s0.x = __shfl_xor(s0.x, 32); s0.y = __shfl_xor(s0.y, 32);
    s0.z = __shfl_xor(s0.z, 32); s0.w = __shfl_xor(s0.w, 32);
    s1.x = __shfl_xor(s1.x, 32); s1.y = __shfl_xor(s1.y, 32);
    s1.z = __shfl_xor(s1.z, 32); s1.w = __shfl_xor(s1.w, 32);
    k0.x = h5 ? q2.x : q0.x; k0.y = h5 ? q2.y : q0.y;
    k0.z = h5 ? q2.z : q0.z; k0.w = h5 ? q2.w : q0.w;
    k1.x = h5 ? q3.x : q1.x; k1.y = h5 ? q3.y : q1.y;
    k1.z = h5 ? q3.z : q1.z; k1.w = h5 ? q3.w : q1.w;
    float4 a0, a1;
    a0.x = k0.x + s0.x; a0.y = k0.y + s0.y; a0.z = k0.z + s0.z; a0.w = k0.w + s0.w;
    a1.x = k1.x + s1.x; a1.y = k1.y + s1.y; a1.z = k1.z + s1.z; a1.w = k1.w + s1.w;
    // stage B: xor 16, exchange 4; class bit2 <- lane bit4
    float4 sB, kB;
    sB.x = h4 ? a0.x : a1.x; sB.y = h4 ? a0.y : a1.y;
    sB.z = h4 ? a0.z : a1.z; sB.w = h4 ? a0.w : a1.w;
    sB.x = __shfl_xor(sB.x, 16); sB.y = __shfl_xor(sB.y, 16);
    sB.z = __shfl_xor(sB.z, 16); sB.w = __shfl_xor(sB.w, 16);
    kB.x = h4 ? a1.x : a0.x; kB.y = h4 ? a1.y : a0.y;
    kB.z = h4 ? a1.z : a0.z; kB.w = h4 ? a1.w : a0.w;
    float4 b;
    b.x = kB.x + sB.x; b.y = kB.y + sB.y; b.z = kB.z + sB.z; b.w = kB.w + sB.w;
    // stage C: xor 8, exchange 2; class bit1 <- lane bit3
    float sCx = h3 ? b.x : b.z, sCy = h3 ? b.y : b.w;
    sCx = __shfl_xor(sCx, 8); sCy = __shfl_xor(sCy, 8);
    float kCx = h3 ? b.z : b.x, kCy = h3 ? b.w : b.y;
    float c2x = kCx + sCx, c2y = kCy + sCy;
    // stage D: xor 4, exchange 1; class bit0 <- lane bit2
    float sD = h2 ? c2x : c2y;
    sD = __shfl_xor(sD, 4);
    float kD = h2 ? c2y : c2x;
    float r = kD + sD;
    // finish over lane bits 0..1
    r += __shfl_xor(r, 1);
    r += __shfl_xor(r, 2);
    return r;
}

// ---- GEMM: Hb = X @ W (bf16 out) + fused a_s/a_d; full graph then group graph ----
__global__ __launch_bounds__(256) void gemm_both_kernel(
        const float* __restrict__ Xf, const float* __restrict__ Wf,
        const float* __restrict__ asf, const float* __restrict__ adf,
        u16* __restrict__ Hbf, float* __restrict__ as_f, float* __restrict__ ad_f, int N,
        const float* __restrict__ Xg, const float* __restrict__ Wg,
        const float* __restrict__ asg, const float* __restrict__ adg,
        u16* __restrict__ Hbg, float* __restrict__ as_g, float* __restrict__ ad_g, int G,
        int nbFull) {
    const float* X; const float* W; const float* av; const float* dv;
    u16* Hb; float* as_out; float* ad_out; int n_lim; long base;
    if (blockIdx.x < nbFull) {
        X = Xf; W = Wf; av = asf; dv = adf; Hb = Hbf; as_out = as_f; ad_out = ad_f;
        n_lim = N; base = (long)blockIdx.x * 32;
    } else {
        X = Xg; W = Wg; av = asg; dv = adg; Hb = Hbg; as_out = as_g; ad_out = ad_g;
        n_lim = G; base = (long)(blockIdx.x - nbFull) * 32;
    }
    __shared__ float Ws[64 * 128];
    __shared__ float Xs[32 * 128];
    int tid = threadIdx.x;
    float4* Ws4 = (float4*)Ws;
    float4* Xs4 = (float4*)Xs;
    const float4* X4 = (const float4*)(X + base * 128);
    for (int i = tid; i < 1024; i += 256) {
        int r = i >> 5;
        Xs4[i] = (base + r < n_lim) ? X4[i] : make_float4(0.f, 0.f, 0.f, 0.f);
    }
    int fgrp = tid & 31;
    int n0 = (tid >> 5) * 4;
    float4 acc[4] = {};
    for (int half = 0; half < 2; ++half) {
        __syncthreads();
        const float4* W4 = (const float4*)(W + half * 64 * 128);
        for (int i = tid; i < 2048; i += 256) Ws4[i] = W4[i];
        __syncthreads();
        #pragma unroll 4
        for (int kk = 0; kk < 64; ++kk) {
            float4 w = Ws4[kk * 32 + fgrp];
            #pragma unroll
            for (int j = 0; j < 4; ++j) {
                float x = Xs[(n0 + j) * 128 + half * 64 + kk];
                acc[j].x += x * w.x; acc[j].y += x * w.y;
                acc[j].z += x * w.z; acc[j].w += x * w.w;
            }
        }
    }
    float4 as4 = ((const float4*)av)[fgrp];
    float4 ad4 = ((const float4*)dv)[fgrp];
    float ps[4], pd[4];
    #pragma unroll
    for (int j = 0; j < 4; ++j) {
        ps[j] = acc[j].x * as4.x + acc[j].y * as4.y + acc[j].z * as4.z + acc[j].w * as4.w;
        pd[j] = acc[j].x * ad4.x + acc[j].y * ad4.y + acc[j].z * ad4.z + acc[j].w * ad4.w;
    }
    #pragma unroll
    for (int off = 16; off; off >>= 1) {
        #pragma unroll
        for (int j = 0; j < 4; ++j) {
            ps[j] += __shfl_xor(ps[j], off);
            pd[j] += __shfl_xor(pd[j], off);
        }
    }
    if ((tid & 31) == 0) {
        #pragma unroll
        for (int j = 0; j < 4; ++j) {
            long n = base + n0 + j;
            if (n < n_lim) { as_out[n] = ps[j]; ad_out[n] = pd[j]; }
        }
    }
    #pragma unroll
    for (int j = 0; j < 4; ++j) {
        long n = base + n0 + j;
        if (n < n_lim) {
            ushort4 hv;
            hv.x = f2bf(acc[j].x); hv.y = f2bf(acc[j].y);
            hv.z = f2bf(acc[j].z); hv.w = f2bf(acc[j].w);
            ((ushort4*)(Hb + n * 128))[fgrp] = hv;
        }
    }
}

// ---------------- merged CSR build over both graphs ----------------
__global__ __launch_bounds__(256) void hist2_kernel(const int* __restrict__ efd, int E, int N,
                                                    const int* __restrict__ egd, int Eg, int G,
                                                    int Npad, int* __restrict__ deg) {
    int i = blockIdx.x * 256 + threadIdx.x;
    int totF = E + N;
    int tot = totF + Eg + G;
    if (i >= tot) return;
    int d;
    if (i < E) d = efd[i];
    else if (i < totF) d = i - E;
    else {
        int j = i - totF;
        d = Npad + ((j < Eg) ? egd[j] : (j - Eg));
    }
    atomicAdd(&deg[d], 1);
}

__global__ __launch_bounds__(256) void scan1_kernel(const int* __restrict__ deg, int n,
                                                    int* __restrict__ bsum) {
    __shared__ int s[256];
    int i = blockIdx.x * 256 + threadIdx.x;
    s[threadIdx.x] = (i < n) ? deg[i] : 0;
    __syncthreads();
    for (int off = 128; off; off >>= 1) {
        if (threadIdx.x < off) s[threadIdx.x] += s[threadIdx.x + off];
        __syncthreads();
    }
    if (threadIdx.x == 0) bsum[blockIdx.x] = s[0];
}

__global__ __launch_bounds__(256) void scan3_kernel(int* __restrict__ deg, int n, int nb,
                                                    const int* __restrict__ bsum,
                                                    int* __restrict__ offs, int Ltot) {
    __shared__ int sb[256];
    __shared__ int s[256];
    int t = threadIdx.x;
    sb[t] = (t < nb) ? bsum[t] : 0;
    __syncthreads();
    for (int off = 1; off < 256; off <<= 1) {
        int u = (t >= off) ? sb[t - off] : 0;
        __syncthreads();
        sb[t] += u;
        __syncthreads();
    }
    int blockOff = (blockIdx.x == 0) ? 0 : sb[blockIdx.x - 1];
    if (blockIdx.x == 0 && t == 0) offs[Ltot] = sb[nb - 1];

    int i = blockIdx.x * 256 + t;
    int v = (i < n) ? deg[i] : 0;
    s[t] = v;
    __syncthreads();
    for (int off = 1; off < 256; off <<= 1) {
        int u = (t >= off) ? s[t - off] : 0;
        __syncthreads();
        s[t] += u;
        __syncthreads();
    }
    if (i < n) {
        int excl = s[t] - v + blockOff;
        offs[i] = excl;
        deg[i] = excl;
    }
}

__global__ __launch_bounds__(256) void place2_kernel(const int* __restrict__ efs,
                                                     const int* __restrict__ efd, int E, int N,
                                                     const int* __restrict__ egs,
                                                     const int* __restrict__ egd, int Eg, int G,
                                                     int Npad,
                                                     const float* __restrict__ a_s,
                                                     const float* __restrict__ a_d,
                                                     const float* __restrict__ a_sg,
                                                     const float* __restrict__ a_dg,
                                                     int* __restrict__ cursor,
                                                     int* __restrict__ slot,
                                                     float* __restrict__ eslot) {
    int i = blockIdx.x * 256 + threadIdx.x;
    int totF = E + N;
    int tot = totF + Eg + G;
    if (i >= tot) return;
    int s, d, dcur;
    float av;
    if (i < totF) {
        if (i < E) { s = efs[i]; d = efd[i]; } else { s = d = i - E; }
        av = a_s[s] + a_d[d];
        dcur = d;
    } else {
        int j = i - totF;
        if (j < Eg) { s = egs[j]; d = egd[j]; } else { s = d = j - Eg; }
        av = a_sg[s] + a_dg[d];
        dcur = Npad + d;
    }
    float e = expf(lrelu(av));  // max-subtract skipped: alpha identical, no overflow
    int pos = atomicAdd(&cursor[dcur], 1);
    slot[pos] = s;
    eslot[pos] = e;
}

// ---- pull: out = elu(sum(e*h)/sum(e) + bias); full-graph waves also emit fxW = fx@fcW ----
__global__ __launch_bounds__(256) void pull2_kernel(const u16* __restrict__ Hf,
                                                    const u16* __restrict__ Hg,
                                                    const int* __restrict__ offs,
                                                    const int* __restrict__ slot,
                                                    const float* __restrict__ eslot,
                                                    const float* __restrict__ bias_f,
                                                    const float* __restrict__ bias_g,
                                                    const float* __restrict__ fcW,
                                                    float* __restrict__ fx,
                                                    float* __restrict__ gx,
                                                    float* __restrict__ fxW,
                                                    int N, int G, int Npad) {
    int gid = blockIdx.x * 256 + threadIdx.x;
    int w = gid >> 6, lane = gid & 63;
    const u16* H;
    const float* bias;
    float* out;
    int idx;
    bool isFull = (w < N);
    if (isFull) {
        H = Hf; bias = bias_f; out = fx + (long)w * 128; idx = w;
    } else if (w < N + G) {
        int g = w - N;
        H = Hg; bias = bias_g; out = gx + (long)g * 128; idx = Npad + g;
    } else return;
    int beg = offs[idx], end = offs[idx + 1];
    float accx = 0.f, accy = 0.f, ssum = 0.f;
    int k = beg;
    for (; k + 2 <= end; k += 2) {
        int s0 = slot[k], s1 = slot[k + 1];
        float e0 = eslot[k], e1 = eslot[k + 1];
        ushort2 h0 = ((const ushort2*)H)[(long)s0 * 64 + lane];
        ushort2 h1 = ((const ushort2*)H)[(long)s1 * 64 + lane];
        accx += e0 * bf2f(h0.x) + e1 * bf2f(h1.x);
        accy += e0 * bf2f(h0.y) + e1 * bf2f(h1.y);
        ssum += e0 + e1;
    }
    if (k < end) {
        int s0 = slot[k];
        float e0 = eslot[k];
        ushort2 h0 = ((const ushort2*)H)[(long)s0 * 64 + lane];
        accx += e0 * bf2f(h0.x);
        accy += e0 * bf2f(h0.y);
        ssum += e0;
    }
    float inv = 1.f / ssum;
    float2 b = ((const float2*)bias)[lane];
    float ox = accx * inv + b.x;
    float oy = accy * inv + b.y;
    ox = ox > 0.f ? ox : expm1f(ox);
    oy = oy > 0.f ? oy : expm1f(oy);
    ((float2*)out)[lane] = make_float2(ox, oy);
    if (isFull) {  // fused FC projection: fxW[w][cls] = fx[w] @ fcW (no bias)
        float r = fc_reduce16(ox, oy, lane, (const float4*)fcW);
        int cls = (lane >> 2) & 15;
        if ((lane & 3) == 0) fxW[(long)w * 16 + cls] = r;
    }
}

// ---------------- adjacent-group sum (atomics; tiny graph) ----------------
__global__ __launch_bounds__(256) void adj_kernel(const int* __restrict__ gsrc,
                                                  const int* __restrict__ gdst, int Eg,
                                                  const float* __restrict__ gx,
                                                  float* __restrict__ adj_sum,
                                                  float* __restrict__ cnt) {
    int gid = blockIdx.x * 256 + threadIdx.x;
    int i = gid >> 6, lane = gid & 63;
    if (i >= Eg) return;
    int s = gsrc[i], d = gdst[i];
    float2 gv = ((const float2*)gx)[(long)d * 64 + lane];
    atomicAdd(&adj_sum[(long)s * 128 + 2 * lane], gv.x);
    atomicAdd(&adj_sum[(long)s * 128 + 2 * lane + 1], gv.y);
    if (lane == 0) atomicAdd(&cnt[s], 1.f);
}

// ---- per-group: adj_mean row + FC projections gfW = gx@fcW, amW = adj_mean@fcW ----
__global__ __launch_bounds__(256) void groupfc_kernel(const float* __restrict__ gx,
                                                      const float* __restrict__ adj_sum,
                                                      const float* __restrict__ cnt,
                                                      const float* __restrict__ fcW,
                                                      float* __restrict__ adj_mean,
                                                      float* __restrict__ gfW,
                                                      float* __restrict__ amW, int G) {
    int gid = blockIdx.x * 256 + threadIdx.x;
    int g = gid >> 6, lane = gid & 63;
    if (g >= G) return;
    float inv = 1.f / fmaxf(cnt[g], 1.f);
    float2 as2 = ((const float2*)adj_sum)[(long)g * 64 + lane];
    float2 am = make_float2(as2.x * inv, as2.y * inv);
    ((float2*)adj_mean)[(long)g * 64 + lane] = am;
    float2 gf = ((const float2*)gx)[(long)g * 64 + lane];
    const float4* fW4 = (const float4*)fcW;
    float rg = fc_reduce16(gf.x, gf.y, lane, fW4);
    float ra = fc_reduce16(am.x, am.y, lane, fW4);
    int cls = (lane >> 2) & 15;
    if ((lane & 3) == 0) {
        gfW[(long)g * 16 + cls] = rg;
        amW[(long)g * 16 + cls] = ra;
    }
}

// ---- final: dots + in-place updated; out via precomputed projections (no matvec) ----
__global__ __launch_bounds__(256) void final3_kernel(const int* __restrict__ node_group,
                                                     const float* __restrict__ gx,
                                                     const float* __restrict__ adj_mean,
                                                     const float* __restrict__ gfW,
                                                     const float* __restrict__ amW,
                                                     const float* __restrict__ fxW,
                                                     const float* __restrict__ fcb,
                                                     float* __restrict__ upd,
                                                     float* __restrict__ out, int N) {
    int gid = blockIdx.x * 256 + threadIdx.x;
    int n = gid >> 6, lane = gid & 63;
    if (n >= N) return;
    int g = node_group[n];
    float2 row = ((const float2*)upd)[(long)n * 64 + lane];
    float2 gf = ((const float2*)gx)[(long)g * 64 + lane];
    float2 am = ((const float2*)adj_mean)[(long)g * 64 + lane];
    float pg = row.x * gf.x + row.y * gf.y;
    float pa = row.x * am.x + row.y * am.y;
    #pragma unroll
    for (int off = 32; off; off >>= 1) {
        pg += __shfl_xor(pg, off);
        pa += __shfl_xor(pa, off);
    }
    float ux = row.x + pg * gf.x + pa * am.x;
    float uy = row.y + pg * gf.y + pa * am.y;
    ((float2*)upd)[(long)n * 64 + lane] = make_float2(ux, uy);
    if (lane < 16) {
        out[(long)n * 16 + lane] = fxW[(long)n * 16 + lane] + pg * gfW[(long)g * 16 + lane] +
                                   pa * amW[(long)g * 16 + lane] + fcb[lane];
    }
}

extern "C" void kernel_launch(void* const* d_in, const int* in_sizes, int n_in,
                              void* d_out, int out_size, void* d_ws, size_t ws_size,
                              hipStream_t stream) {
    const float* x_full = (const float*)d_in[0];
    const float* x_group = (const float*)d_in[1];
    const float* W_full = (const float*)d_in[2];
    const float* a_src_full = (const float*)d_in[3];
    const float* a_dst_full = (const float*)d_in[4];
    const float* bias_full = (const float*)d_in[5];
    const float* W_group = (const float*)d_in[6];
    const float* a_src_g = (const float*)d_in[7];
    const float* a_dst_g = (const float*)d_in[8];
    const float* bias_g = (const float*)d_in[9];
    const float* fc_W = (const float*)d_in[10];
    const float* fc_b = (const float*)d_in[11];
    const int* ef = (const int*)d_in[12];
    const int* eg = (const int*)d_in[13];
    const int* node_group = (const int*)d_in[14];

    int N = in_sizes[0] / 128;
    int G = in_sizes[1] / 128;
    int E = in_sizes[12] / 2;
    int Eg = in_sizes[13] / 2;
    const int* ef_src = ef;
    const int* ef_dst = ef + E;
    const int* eg_src = eg;
    const int* eg_dst = eg + Eg;

    int Npad = (N + 255) & ~255;
    int Ltot = Npad + G;
    int LtotPad = (Ltot + 255) & ~255;
    int totF = E + N;
    int tot = totF + Eg + G;

    float* out_cls = (float*)d_out;
    float* fx = out_cls + (long)N * 16;  // fullx_elu scratch, becomes `updated`

    char* w = (char*)d_ws;
    auto alloc = [&](size_t bytes) {
        char* p = w;
        w += (bytes + 255) & ~(size_t)255;
        return p;
    };
    u16* h_full = (u16*)alloc((size_t)N * 128 * 2);
    u16* h_g = (u16*)alloc((size_t)G * 128 * 2);
    float* a_s = (float*)alloc((size_t)N * 4);
    float* a_d = (float*)alloc((size_t)N * 4);
    float* a_sg = (float*)alloc((size_t)G * 4);
    float* a_dg = (float*)alloc((size_t)G * 4);
    float* gx = (float*)alloc((size_t)G * 128 * 4);
    float* adj_mean = (float*)alloc((size_t)G * 128 * 4);
    float* fxW = (float*)alloc((size_t)N * 16 * 4);
    float* gfW = (float*)alloc((size_t)G * 16 * 4);
    float* amW = (float*)alloc((size_t)G * 16 * 4);
    // zero-init span: adj_sum, cnt, deg (contiguous, one memset)
    float* adj_sum = (float*)alloc((size_t)G * 128 * 4);
    float* cnt = (float*)alloc((size_t)G * 4);
    int* deg = (int*)alloc((size_t)LtotPad * 4);
    int* offs = (int*)alloc((size_t)(LtotPad + 1) * 4);
    int* slot = (int*)alloc((size_t)tot * 4);
    float* eslot = (float*)alloc((size_t)tot * 4);
    int* bsum = (int*)alloc(256 * 4);

    size_t zero_span = (char*)(deg + LtotPad) - (char*)adj_sum;
    (void)hipMemsetAsync(adj_sum, 0, zero_span, stream);

    auto cdiv = [](int a, int b) { return (a + b - 1) / b; };

    // feature transforms + fused attention scalars (both graphs, one launch)
    int nbFull = cdiv(N, 32);
    gemm_both_kernel<<<nbFull + cdiv(G, 32), 256, 0, stream>>>(
        x_full, W_full, a_src_full, a_dst_full, h_full, a_s, a_d, N,
        x_group, W_group, a_src_g, a_dst_g, h_g, a_sg, a_dg, G, nbFull);

    // merged CSR build
    int nb = cdiv(Ltot, 256);
    hist2_kernel<<<cdiv(tot, 256), 256, 0, stream>>>(ef_dst, E, N, eg_dst, Eg, G, Npad, deg);
    scan1_kernel<<<nb, 256, 0, stream>>>(deg, Ltot, bsum);
    scan3_kernel<<<nb, 256, 0, stream>>>(deg, Ltot, nb, bsum, offs, Ltot);
    place2_kernel<<<cdiv(tot, 256), 256, 0, stream>>>(ef_src, ef_dst, E, N, eg_src, eg_dst,
                                                      Eg, G, Npad, a_s, a_d, a_sg, a_dg,
                                                      deg, slot, eslot);

    // pull aggregation for both graphs (+ fused fxW projection for full nodes)
    pull2_kernel<<<cdiv((N + G) * 64, 256), 256, 0, stream>>>(h_full, h_g, offs, slot, eslot,
                                                              bias_full, bias_g, fc_W,
                                                              fx, gx, fxW, N, G, Npad);

    // adjacent-group sum -> per-group mean + FC projections -> slim final
    adj_kernel<<<cdiv(Eg * 64, 256), 256, 0, stream>>>(eg_src, eg_dst, Eg, gx, adj_sum, cnt);
    groupfc_kernel<<<cdiv(G * 64, 256), 256, 0, stream>>>(gx, adj_sum, cnt, fc_W,
                                                          adj_mean, gfW, amW, G);
    final3_kernel<<<cdiv(N * 64, 256), 256, 0, stream>>>(node_group, gx, adj_mean, gfW, amW,
                                                         fxW, fc_b, fx, out_cls, N);
}

// Round 8
// 289.123 us; speedup vs baseline: 1.1680x; 1.0910x over previous
//
#include <hip/hip_runtime.h>

typedef unsigned short u16;
typedef unsigned int u32;

static __device__ __forceinline__ float lrelu(float x) { return x >= 0.f ? x : 0.2f * x; }

static __device__ __forceinline__ u16 f2bf(float f) {
    u32 u = __float_as_uint(f);
    u += 0x7FFF + ((u >> 16) & 1);
    return (u16)(u >> 16);
}
static __device__ __forceinline__ float bf2f(u16 h) {
    return __uint_as_float((u32)h << 16);
}

// 128->16 matvec across one wave: lane holds features (2*lane, 2*lane+1) = (f0,f1).
// Returns class ((lane>>2)&15)'s sum (valid where (lane&3)==0).
// Exchange-halves reduction, 17 shfl, all named registers (no arrays -> no scratch).
static __device__ __forceinline__ float fc_reduce16(float f0, float f1, int lane,
                                                    const float4* __restrict__ fW4) {
    float4 w00 = fW4[(2 * lane) * 4 + 0], w01 = fW4[(2 * lane) * 4 + 1];
    float4 w02 = fW4[(2 * lane) * 4 + 2], w03 = fW4[(2 * lane) * 4 + 3];
    float4 w10 = fW4[(2 * lane + 1) * 4 + 0], w11 = fW4[(2 * lane + 1) * 4 + 1];
    float4 w12 = fW4[(2 * lane + 1) * 4 + 2], w13 = fW4[(2 * lane + 1) * 4 + 3];
    float4 q0, q1, q2, q3;
    q0.x = f0 * w00.x + f1 * w10.x; q0.y = f0 * w00.y + f1 * w10.y;
    q0.z = f0 * w00.z + f1 * w10.z; q0.w = f0 * w00.w + f1 * w10.w;
    q1.x = f0 * w01.x + f1 * w11.x; q1.y = f0 * w01.y + f1 * w11.y;
    q1.z = f0 * w01.z + f1 * w11.z; q1.w = f0 * w01.w + f1 * w11.w;
    q2.x = f0 * w02.x + f1 * w12.x; q2.y = f0 * w02.y + f1 * w12.y;
    q2.z = f0 * w02.z + f1 * w12.z; q2.w = f0 * w02.w + f1 * w12.w;
    q3.x = f0 * w03.x + f1 * w13.x; q3.y = f0 * w03.y + f1 * w13.y;
    q3.z = f0 * w03.z + f1 * w13.z; q3.w = f0 * w03.w + f1 * w13.w;
    bool h5 = (lane & 32) != 0, h4 = (lane & 16) != 0;
    bool h3 = (lane & 8) != 0, h2 = (lane & 4) != 0;
    float4 s0, s1, k0, k1;
    s0.x = h5 ? q0.x : q2.x; s0.y = h5 ? q0.y : q2.y;
    s0.z = h5 ? q0.z : q2.z; s0.w = h5 ? q0.w : q2.w;
    s1.x = h5 ? q1.x : q3.x; s1.y = h5 ? q1.y : q3.y;
    s1.z = h5 ? q1.z : q3.z; s1.w = h5 ? q1.w : q3.w;
    s0.x = __shfl_xor(s0.x, 32); s0.y = __shfl_xor(s0.y, 32);
    s0.z = __shfl_xor(s0.z, 32); s0.w = __shfl_xor(s0.w, 32);
    s1.x = __shfl_xor(s1.x, 32); s1.y = __shfl_xor(s1.y, 32);
    s1.z = __shfl_xor(s1.z, 32); s1.w = __shfl_xor(s1.w, 32);
    k0.x = h5 ? q2.x : q0.x; k0.y = h5 ? q2.y : q0.y;
    k0.z = h5 ? q2.z : q0.z; k0.w = h5 ? q2.w : q0.w;
    k1.x = h5 ? q3.x : q1.x; k1.y = h5 ? q3.y : q1.y;
    k1.z = h5 ? q3.z : q1.z; k1.w = h5 ? q3.w : q1.w;
    float4 a0, a1;
    a0.x = k0.x + s0.x; a0.y = k0.y + s0.y; a0.z = k0.z + s0.z; a0.w = k0.w + s0.w;
    a1.x = k1.x + s1.x; a1.y = k1.y + s1.y; a1.z = k1.z + s1.z; a1.w = k1.w + s1.w;
    float4 sB, kB;
    sB.x = h4 ? a0.x : a1.x; sB.y = h4 ? a0.y : a1.y;
    sB.z = h4 ? a0.z : a1.z; sB.w = h4 ? a0.w : a1.w;
    sB.x = __shfl_xor(sB.x, 16); sB.y = __shfl_xor(sB.y, 16);
    sB.z = __shfl_xor(sB.z, 16); sB.w = __shfl_xor(sB.w, 16);
    kB.x = h4 ? a1.x : a0.x; kB.y = h4 ? a1.y : a0.y;
    kB.z = h4 ? a1.z : a0.z; kB.w = h4 ? a1.w : a0.w;
    float4 b;
    b.x = kB.x + sB.x; b.y = kB.y + sB.y; b.z = kB.z + sB.z; b.w = kB.w + sB.w;
    float sCx = h3 ? b.x : b.z, sCy = h3 ? b.y : b.w;
    sCx = __shfl_xor(sCx, 8); sCy = __shfl_xor(sCy, 8);
    float kCx = h3 ? b.z : b.x, kCy = h3 ? b.w : b.y;
    float c2x = kCx + sCx, c2y = kCy + sCy;
    float sD = h2 ? c2x : c2y;
    sD = __shfl_xor(sD, 4);
    float kD = h2 ? c2y : c2x;
    float r = kD + sD;
    r += __shfl_xor(r, 1);
    r += __shfl_xor(r, 2);
    return r;
}

// ---- GEMM: Hb = X @ W (bf16 out) + fused a_s/a_d; full graph then group graph ----
__global__ __launch_bounds__(256) void gemm_both_kernel(
        const float* __restrict__ Xf, const float* __restrict__ Wf,
        const float* __restrict__ asf, const float* __restrict__ adf,
        u16* __restrict__ Hbf, float* __restrict__ as_f, float* __restrict__ ad_f, int N,
        const float* __restrict__ Xg, const float* __restrict__ Wg,
        const float* __restrict__ asg, const float* __restrict__ adg,
        u16* __restrict__ Hbg, float* __restrict__ as_g, float* __restrict__ ad_g, int G,
        int nbFull) {
    const float* X; const float* W; const float* av; const float* dv;
    u16* Hb; float* as_out; float* ad_out; int n_lim; long base;
    if (blockIdx.x < nbFull) {
        X = Xf; W = Wf; av = asf; dv = adf; Hb = Hbf; as_out = as_f; ad_out = ad_f;
        n_lim = N; base = (long)blockIdx.x * 32;
    } else {
        X = Xg; W = Wg; av = asg; dv = adg; Hb = Hbg; as_out = as_g; ad_out = ad_g;
        n_lim = G; base = (long)(blockIdx.x - nbFull) * 32;
    }
    __shared__ float Ws[64 * 128];
    __shared__ float Xs[32 * 128];
    int tid = threadIdx.x;
    float4* Ws4 = (float4*)Ws;
    float4* Xs4 = (float4*)Xs;
    const float4* X4 = (const float4*)(X + base * 128);
    for (int i = tid; i < 1024; i += 256) {
        int r = i >> 5;
        Xs4[i] = (base + r < n_lim) ? X4[i] : make_float4(0.f, 0.f, 0.f, 0.f);
    }
    int fgrp = tid & 31;
    int n0 = (tid >> 5) * 4;
    float4 acc[4] = {};
    for (int half = 0; half < 2; ++half) {
        __syncthreads();
        const float4* W4 = (const float4*)(W + half * 64 * 128);
        for (int i = tid; i < 2048; i += 256) Ws4[i] = W4[i];
        __syncthreads();
        #pragma unroll 4
        for (int kk = 0; kk < 64; ++kk) {
            float4 w = Ws4[kk * 32 + fgrp];
            #pragma unroll
            for (int j = 0; j < 4; ++j) {
                float x = Xs[(n0 + j) * 128 + half * 64 + kk];
                acc[j].x += x * w.x; acc[j].y += x * w.y;
                acc[j].z += x * w.z; acc[j].w += x * w.w;
            }
        }
    }
    float4 as4 = ((const float4*)av)[fgrp];
    float4 ad4 = ((const float4*)dv)[fgrp];
    float ps[4], pd[4];
    #pragma unroll
    for (int j = 0; j < 4; ++j) {
        ps[j] = acc[j].x * as4.x + acc[j].y * as4.y + acc[j].z * as4.z + acc[j].w * as4.w;
        pd[j] = acc[j].x * ad4.x + acc[j].y * ad4.y + acc[j].z * ad4.z + acc[j].w * ad4.w;
    }
    #pragma unroll
    for (int off = 16; off; off >>= 1) {
        #pragma unroll
        for (int j = 0; j < 4; ++j) {
            ps[j] += __shfl_xor(ps[j], off);
            pd[j] += __shfl_xor(pd[j], off);
        }
    }
    if ((tid & 31) == 0) {
        #pragma unroll
        for (int j = 0; j < 4; ++j) {
            long n = base + n0 + j;
            if (n < n_lim) { as_out[n] = ps[j]; ad_out[n] = pd[j]; }
        }
    }
    #pragma unroll
    for (int j = 0; j < 4; ++j) {
        long n = base + n0 + j;
        if (n < n_lim) {
            ushort4 hv;
            hv.x = f2bf(acc[j].x); hv.y = f2bf(acc[j].y);
            hv.z = f2bf(acc[j].z); hv.w = f2bf(acc[j].w);
            ((ushort4*)(Hb + n * 128))[fgrp] = hv;
        }
    }
}

// ---------------- merged CSR build over both graphs ----------------
__global__ __launch_bounds__(256) void hist2_kernel(const int* __restrict__ efd, int E, int N,
                                                    const int* __restrict__ egd, int Eg, int G,
                                                    int Npad, int* __restrict__ deg) {
    int i = blockIdx.x * 256 + threadIdx.x;
    int totF = E + N;
    int tot = totF + Eg + G;
    if (i >= tot) return;
    int d;
    if (i < E) d = efd[i];
    else if (i < totF) d = i - E;
    else {
        int j = i - totF;
        d = Npad + ((j < Eg) ? egd[j] : (j - Eg));
    }
    atomicAdd(&deg[d], 1);
}

__global__ __launch_bounds__(256) void scan1_kernel(const int* __restrict__ deg, int n,
                                                    int* __restrict__ bsum) {
    __shared__ int s[256];
    int i = blockIdx.x * 256 + threadIdx.x;
    s[threadIdx.x] = (i < n) ? deg[i] : 0;
    __syncthreads();
    for (int off = 128; off; off >>= 1) {
        if (threadIdx.x < off) s[threadIdx.x] += s[threadIdx.x + off];
        __syncthreads();
    }
    if (threadIdx.x == 0) bsum[blockIdx.x] = s[0];
}

__global__ __launch_bounds__(256) void scan3_kernel(int* __restrict__ deg, int n, int nb,
                                                    const int* __restrict__ bsum,
                                                    int* __restrict__ offs, int Ltot) {
    __shared__ int sb[256];
    __shared__ int s[256];
    int t = threadIdx.x;
    sb[t] = (t < nb) ? bsum[t] : 0;
    __syncthreads();
    for (int off = 1; off < 256; off <<= 1) {
        int u = (t >= off) ? sb[t - off] : 0;
        __syncthreads();
        sb[t] += u;
        __syncthreads();
    }
    int blockOff = (blockIdx.x == 0) ? 0 : sb[blockIdx.x - 1];
    if (blockIdx.x == 0 && t == 0) offs[Ltot] = sb[nb - 1];

    int i = blockIdx.x * 256 + t;
    int v = (i < n) ? deg[i] : 0;
    s[t] = v;
    __syncthreads();
    for (int off = 1; off < 256; off <<= 1) {
        int u = (t >= off) ? s[t - off] : 0;
        __syncthreads();
        s[t] += u;
        __syncthreads();
    }
    if (i < n) {
        int excl = s[t] - v + blockOff;
        offs[i] = excl;
        deg[i] = excl;
    }
}

// placement: packed (src, e) per edge; e = exp(lrelu(a_s[src]+a_d[dst])) computed ONCE
__global__ __launch_bounds__(256) void place2_kernel(const int* __restrict__ efs,
                                                     const int* __restrict__ efd, int E, int N,
                                                     const int* __restrict__ egs,
                                                     const int* __restrict__ egd, int Eg, int G,
                                                     int Npad,
                                                     const float* __restrict__ a_s,
                                                     const float* __restrict__ a_d,
                                                     const float* __restrict__ a_sg,
                                                     const float* __restrict__ a_dg,
                                                     int* __restrict__ cursor,
                                                     int2* __restrict__ sepack) {
    int i = blockIdx.x * 256 + threadIdx.x;
    int totF = E + N;
    int tot = totF + Eg + G;
    if (i >= tot) return;
    int s, d, dcur;
    float av;
    if (i < totF) {
        if (i < E) { s = efs[i]; d = efd[i]; } else { s = d = i - E; }
        av = a_s[s] + a_d[d];
        dcur = d;
    } else {
        int j = i - totF;
        if (j < Eg) { s = egs[j]; d = egd[j]; } else { s = d = j - Eg; }
        av = a_sg[s] + a_dg[d];
        dcur = Npad + d;
    }
    float e = expf(lrelu(av));  // max-subtract skipped: alpha identical, no overflow
    int pos = atomicAdd(&cursor[dcur], 1);
    sepack[pos] = make_int2(s, __float_as_int(e));
}

// ---- pull: out = elu(sum(e*h)/sum(e) + bias); full-graph waves also emit fxW = fx@fcW ----
// Edge (src,e) pairs are prefetched lane-parallel (one 8B coalesced load covers 64 edges),
// then broadcast via __shfl -> gather addresses have no load-dependency; 4 gathers in flight.
__global__ __launch_bounds__(256) void pull2_kernel(const u16* __restrict__ Hf,
                                                    const u16* __restrict__ Hg,
                                                    const int* __restrict__ offs,
                                                    const int2* __restrict__ sepack,
                                                    const float* __restrict__ bias_f,
                                                    const float* __restrict__ bias_g,
                                                    const float* __restrict__ fcW,
                                                    float* __restrict__ fx,
                                                    float* __restrict__ gx,
                                                    float* __restrict__ fxW,
                                                    int N, int G, int Npad) {
    int gid = blockIdx.x * 256 + threadIdx.x;
    int w = gid >> 6, lane = gid & 63;
    const u16* H;
    const float* bias;
    float* out;
    int idx;
    bool isFull = (w < N);
    if (isFull) {
        H = Hf; bias = bias_f; out = fx + (long)w * 128; idx = w;
    } else if (w < N + G) {
        int g = w - N;
        H = Hg; bias = bias_g; out = gx + (long)g * 128; idx = Npad + g;
    } else return;
    int beg = offs[idx], end = offs[idx + 1];
    const ushort2* H2 = (const ushort2*)H;
    float a0x = 0.f, a0y = 0.f, a1x = 0.f, a1y = 0.f;
    float a2x = 0.f, a2y = 0.f, a3x = 0.f, a3y = 0.f;
    float ss0 = 0.f, ss1 = 0.f;
    for (int b = beg; b < end; b += 64) {
        int m = end - b;
        if (m > 64) m = 64;
        int2 se = (lane < m) ? sepack[b + lane] : make_int2(0, 0);
        int sl = se.x;
        float el = __int_as_float(se.y);
        int k = 0;
        for (; k + 4 <= m; k += 4) {
            int s0 = __shfl(sl, k),     s1 = __shfl(sl, k + 1);
            int s2 = __shfl(sl, k + 2), s3 = __shfl(sl, k + 3);
            float e0 = __shfl(el, k),     e1 = __shfl(el, k + 1);
            float e2 = __shfl(el, k + 2), e3 = __shfl(el, k + 3);
            ushort2 h0 = H2[(long)s0 * 64 + lane];
            ushort2 h1 = H2[(long)s1 * 64 + lane];
            ushort2 h2 = H2[(long)s2 * 64 + lane];
            ushort2 h3 = H2[(long)s3 * 64 + lane];
            a0x += e0 * bf2f(h0.x); a0y += e0 * bf2f(h0.y);
            a1x += e1 * bf2f(h1.x); a1y += e1 * bf2f(h1.y);
            a2x += e2 * bf2f(h2.x); a2y += e2 * bf2f(h2.y);
            a3x += e3 * bf2f(h3.x); a3y += e3 * bf2f(h3.y);
            ss0 += e0 + e1; ss1 += e2 + e3;
        }
        for (; k < m; ++k) {
            int s0 = __shfl(sl, k);
            float e0 = __shfl(el, k);
            ushort2 h0 = H2[(long)s0 * 64 + lane];
            a0x += e0 * bf2f(h0.x); a0y += e0 * bf2f(h0.y);
            ss0 += e0;
        }
    }
    float accx = (a0x + a1x) + (a2x + a3x);
    float accy = (a0y + a1y) + (a2y + a3y);
    float ssum = ss0 + ss1;
    float inv = 1.f / ssum;
    float2 bv = ((const float2*)bias)[lane];
    float ox = accx * inv + bv.x;
    float oy = accy * inv + bv.y;
    ox = ox > 0.f ? ox : expm1f(ox);
    oy = oy > 0.f ? oy : expm1f(oy);
    ((float2*)out)[lane] = make_float2(ox, oy);
    if (isFull) {  // fused FC projection: fxW[w][cls] = fx[w] @ fcW (no bias)
        float r = fc_reduce16(ox, oy, lane, (const float4*)fcW);
        int cls = (lane >> 2) & 15;
        if ((lane & 3) == 0) fxW[(long)w * 16 + cls] = r;
    }
}

// ---------------- adjacent-group sum (atomics; tiny graph) ----------------
__global__ __launch_bounds__(256) void adj_kernel(const int* __restrict__ gsrc,
                                                  const int* __restrict__ gdst, int Eg,
                                                  const float* __restrict__ gx,
                                                  float* __restrict__ adj_sum,
                                                  float* __restrict__ cnt) {
    int gid = blockIdx.x * 256 + threadIdx.x;
    int i = gid >> 6, lane = gid & 63;
    if (i >= Eg) return;
    int s = gsrc[i], d = gdst[i];
    float2 gv = ((const float2*)gx)[(long)d * 64 + lane];
    atomicAdd(&adj_sum[(long)s * 128 + 2 * lane], gv.x);
    atomicAdd(&adj_sum[(long)s * 128 + 2 * lane + 1], gv.y);
    if (lane == 0) atomicAdd(&cnt[s], 1.f);
}

// ---- per-group: adj_mean row + FC projections gfW = gx@fcW, amW = adj_mean@fcW ----
__global__ __launch_bounds__(256) void groupfc_kernel(const float* __restrict__ gx,
                                                      const float* __restrict__ adj_sum,
                                                      const float* __restrict__ cnt,
                                                      const float* __restrict__ fcW,
                                                      float* __restrict__ adj_mean,
                                                      float* __restrict__ gfW,
                                                      float* __restrict__ amW, int G) {
    int gid = blockIdx.x * 256 + threadIdx.x;
    int g = gid >> 6, lane = gid & 63;
    if (g >= G) return;
    float inv = 1.f / fmaxf(cnt[g], 1.f);
    float2 as2 = ((const float2*)adj_sum)[(long)g * 64 + lane];
    float2 am = make_float2(as2.x * inv, as2.y * inv);
    ((float2*)adj_mean)[(long)g * 64 + lane] = am;
    float2 gf = ((const float2*)gx)[(long)g * 64 + lane];
    const float4* fW4 = (const float4*)fcW;
    float rg = fc_reduce16(gf.x, gf.y, lane, fW4);
    float ra = fc_reduce16(am.x, am.y, lane, fW4);
    int cls = (lane >> 2) & 15;
    if ((lane & 3) == 0) {
        gfW[(long)g * 16 + cls] = rg;
        amW[(long)g * 16 + cls] = ra;
    }
}

// ---- final: dots + in-place updated; out via precomputed projections (no matvec) ----
__global__ __launch_bounds__(256) void final3_kernel(const int* __restrict__ node_group,
                                                     const float* __restrict__ gx,
                                                     const float* __restrict__ adj_mean,
                                                     const float* __restrict__ gfW,
                                                     const float* __restrict__ amW,
                                                     const float* __restrict__ fxW,
                                                     const float* __restrict__ fcb,
                                                     float* __restrict__ upd,
                                                     float* __restrict__ out, int N) {
    int gid = blockIdx.x * 256 + threadIdx.x;
    int n = gid >> 6, lane = gid & 63;
    if (n >= N) return;
    int g = node_group[n];
    float2 row = ((const float2*)upd)[(long)n * 64 + lane];
    float2 gf = ((const float2*)gx)[(long)g * 64 + lane];
    float2 am = ((const float2*)adj_mean)[(long)g * 64 + lane];
    float pg = row.x * gf.x + row.y * gf.y;
    float pa = row.x * am.x + row.y * am.y;
    #pragma unroll
    for (int off = 32; off; off >>= 1) {
        pg += __shfl_xor(pg, off);
        pa += __shfl_xor(pa, off);
    }
    float ux = row.x + pg * gf.x + pa * am.x;
    float uy = row.y + pg * gf.y + pa * am.y;
    ((float2*)upd)[(long)n * 64 + lane] = make_float2(ux, uy);
    if (lane < 16) {
        out[(long)n * 16 + lane] = fxW[(long)n * 16 + lane] + pg * gfW[(long)g * 16 + lane] +
                                   pa * amW[(long)g * 16 + lane] + fcb[lane];
    }
}

extern "C" void kernel_launch(void* const* d_in, const int* in_sizes, int n_in,
                              void* d_out, int out_size, void* d_ws, size_t ws_size,
                              hipStream_t stream) {
    const float* x_full = (const float*)d_in[0];
    const float* x_group = (const float*)d_in[1];
    const float* W_full = (const float*)d_in[2];
    const float* a_src_full = (const float*)d_in[3];
    const float* a_dst_full = (const float*)d_in[4];
    const float* bias_full = (const float*)d_in[5];
    const float* W_group = (const float*)d_in[6];
    const float* a_src_g = (const float*)d_in[7];
    const float* a_dst_g = (const float*)d_in[8];
    const float* bias_g = (const float*)d_in[9];
    const float* fc_W = (const float*)d_in[10];
    const float* fc_b = (const float*)d_in[11];
    const int* ef = (const int*)d_in[12];
    const int* eg = (const int*)d_in[13];
    const int* node_group = (const int*)d_in[14];

    int N = in_sizes[0] / 128;
    int G = in_sizes[1] / 128;
    int E = in_sizes[12] / 2;
    int Eg = in_sizes[13] / 2;
    const int* ef_src = ef;
    const int* ef_dst = ef + E;
    const int* eg_src = eg;
    const int* eg_dst = eg + Eg;

    int Npad = (N + 255) & ~255;
    int Ltot = Npad + G;
    int LtotPad = (Ltot + 255) & ~255;
    int totF = E + N;
    int tot = totF + Eg + G;

    float* out_cls = (float*)d_out;
    float* fx = out_cls + (long)N * 16;  // fullx_elu scratch, becomes `updated`

    char* w = (char*)d_ws;
    auto alloc = [&](size_t bytes) {
        char* p = w;
        w += (bytes + 255) & ~(size_t)255;
        return p;
    };
    u16* h_full = (u16*)alloc((size_t)N * 128 * 2);
    u16* h_g = (u16*)alloc((size_t)G * 128 * 2);
    float* a_s = (float*)alloc((size_t)N * 4);
    float* a_d = (float*)alloc((size_t)N * 4);
    float* a_sg = (float*)alloc((size_t)G * 4);
    float* a_dg = (float*)alloc((size_t)G * 4);
    float* gx = (float*)alloc((size_t)G * 128 * 4);
    float* adj_mean = (float*)alloc((size_t)G * 128 * 4);
    float* fxW = (float*)alloc((size_t)N * 16 * 4);
    float* gfW = (float*)alloc((size_t)G * 16 * 4);
    float* amW = (float*)alloc((size_t)G * 16 * 4);
    // zero-init span: adj_sum, cnt, deg (contiguous, one memset)
    float* adj_sum = (float*)alloc((size_t)G * 128 * 4);
    float* cnt = (float*)alloc((size_t)G * 4);
    int* deg = (int*)alloc((size_t)LtotPad * 4);
    int* offs = (int*)alloc((size_t)(LtotPad + 1) * 4);
    int2* sepack = (int2*)alloc((size_t)tot * 8);
    int* bsum = (int*)alloc(256 * 4);

    size_t zero_span = (char*)(deg + LtotPad) - (char*)adj_sum;
    (void)hipMemsetAsync(adj_sum, 0, zero_span, stream);

    auto cdiv = [](int a, int b) { return (a + b - 1) / b; };

    // feature transforms + fused attention scalars (both graphs, one launch)
    int nbFull = cdiv(N, 32);
    gemm_both_kernel<<<nbFull + cdiv(G, 32), 256, 0, stream>>>(
        x_full, W_full, a_src_full, a_dst_full, h_full, a_s, a_d, N,
        x_group, W_group, a_src_g, a_dst_g, h_g, a_sg, a_dg, G, nbFull);

    // merged CSR build
    int nb = cdiv(Ltot, 256);
    hist2_kernel<<<cdiv(tot, 256), 256, 0, stream>>>(ef_dst, E, N, eg_dst, Eg, G, Npad, deg);
    scan1_kernel<<<nb, 256, 0, stream>>>(deg, Ltot, bsum);
    scan3_kernel<<<nb, 256, 0, stream>>>(deg, Ltot, nb, bsum, offs, Ltot);
    place2_kernel<<<cdiv(tot, 256), 256, 0, stream>>>(ef_src, ef_dst, E, N, eg_src, eg_dst,
                                                      Eg, G, Npad, a_s, a_d, a_sg, a_dg,
                                                      deg, sepack);

    // pull aggregation for both graphs (+ fused fxW projection for full nodes)
    pull2_kernel<<<cdiv((N + G) * 64, 256), 256, 0, stream>>>(h_full, h_g, offs, sepack,
                                                              bias_full, bias_g, fc_W,
                                                              fx, gx, fxW, N, G, Npad);

    // adjacent-group sum -> per-group mean + FC projections -> slim final
    adj_kernel<<<cdiv(Eg * 64, 256), 256, 0, stream>>>(eg_src, eg_dst, Eg, gx, adj_sum, cnt);
    groupfc_kernel<<<cdiv(G * 64, 256), 256, 0, stream>>>(gx, adj_sum, cnt, fc_W,
                                                          adj_mean, gfW, amW, G);
    final3_kernel<<<cdiv(N * 64, 256), 256, 0, stream>>>(node_group, gx, adj_mean, gfW, amW,
                                                         fxW, fc_b, fx, out_cls, N);
}